// Round 2
// baseline (190.561 us; speedup 1.0000x reference)
//
#include <hip/hip_runtime.h>

namespace {

constexpr int L     = 128;   // Lx = Ly = Lz
constexpr int NANG  = 120;
constexpr int SLICE = L * L;             // elements per (b, angle) slice
constexpr int SLICE_BYTES = SLICE * 4;   // 65536
constexpr int ROW_BYTES   = L * 4;       // 512

typedef float v2f __attribute__((ext_vector_type(2)));

// Byte offsets include the angle term: off = a*SLICE_BYTES + row*ROW_BYTES.
struct alignas(16) WEntry { float w0, w1; int off0, off1; };

// Block: 256 threads = 4 waves. Block covers x = blockIdx.y, y in [ybase, ybase+8).
// Wave w handles y = ybase+w and y = ybase+w+4 (2 points -> 4 loads in flight/iter).
// Lane l: b = l>>5, z-quad = l&31  -> float4 over z. 64 lanes cover all (b,z).
__global__ __launch_bounds__(256) void bp_kernel(
    const float* __restrict__ image,   // [2,120,128,128]
    const float* __restrict__ angles,  // [120] degrees
    float* __restrict__ out)           // [2,128,128,128]
{
    __shared__ WEntry wtab[8 * NANG];  // 15 KiB: one 120-entry table per y
    __shared__ float  nrmtab[8];       // per-y  sum over angles of (w0+w1)

    const int x     = blockIdx.y;
    const int ybase = blockIdx.x * 8;
    const int tid   = threadIdx.x;
    const float cx  = (L - 1) * 0.5f;

    if (tid < 8) nrmtab[tid] = 0.f;
    __syncthreads();

    // ---- Phase 1: per-(y,angle) weights + full byte offsets into LDS ----
    for (int e = tid; e < 8 * NANG; e += 256) {
        const int a = e % NANG;
        const int t = e / NANG;          // table index = y - ybase
        const float phi = -angles[a] * 0.017453292519943295f; // -deg2rad
        float s, c;
        sincosf(phi, &s, &c);
        const float X = (float)x - cx;
        const float Y = (float)(ybase + t) - cx;
        const float sx = c * X + s * Y + cx;
        const float sy = -s * X + c * Y + cx;
        const float x0f = floorf(sx);
        const float y0f = floorf(sy);
        const float wx = sx - x0f;
        const float wy = sy - y0f;
        const int x0 = (int)x0f;
        const int y0 = (int)y0f;
        const float mx0 = (x0 >= 0  && x0 <  L)     ? 1.f : 0.f;
        const float mx1 = (x0 >= -1 && x0 <= L - 2) ? 1.f : 0.f;
        const float my0 = (y0 >= 0  && y0 <  L)     ? 1.f : 0.f;
        const float my1 = (y0 >= -1 && y0 <= L - 2) ? 1.f : 0.f;
        const float A = (1.f - wx) * mx0 + wx * mx1;
        const int y0c = min(max(y0, 0), L - 1);
        const int y1c = min(max(y0 + 1, 0), L - 1);
        WEntry we;
        we.w0   = (1.f - wy) * my0 * A;
        we.w1   = wy * my1 * A;
        we.off0 = a * SLICE_BYTES + y0c * ROW_BYTES;
        we.off1 = a * SLICE_BYTES + y1c * ROW_BYTES;
        wtab[t * NANG + a] = we;
        atomicAdd(&nrmtab[t], we.w0 + we.w1);
    }
    __syncthreads();

    // ---- Phase 2: accumulate over angles ----
    const int wave = tid >> 6;
    const int lane = tid & 63;
    const int b    = lane >> 5;
    const int zq   = lane & 31;               // z-quad index
    const uint32_t lane_off = (uint32_t)(b * NANG * SLICE + zq * 4) * 4u; // bytes

    const char* __restrict__ imgc = (const char*)image;
    const WEntry* __restrict__ wtA = &wtab[wave * NANG];
    const WEntry* __restrict__ wtB = &wtab[(wave + 4) * NANG];

    v2f accA0 = {0.f, 0.f}, accA1 = {0.f, 0.f};
    v2f accB0 = {0.f, 0.f}, accB1 = {0.f, 0.f};

#pragma unroll 4
    for (int a = 0; a < NANG; ++a) {
        const WEntry ea = wtA[a];             // wave-uniform ds_read_b128 broadcast
        const WEntry eb = wtB[a];
        const float4 va0 = *(const float4*)(imgc + (lane_off + (uint32_t)ea.off0));
        const float4 va1 = *(const float4*)(imgc + (lane_off + (uint32_t)ea.off1));
        const float4 vb0 = *(const float4*)(imgc + (lane_off + (uint32_t)eb.off0));
        const float4 vb1 = *(const float4*)(imgc + (lane_off + (uint32_t)eb.off1));

        const v2f* pa0 = (const v2f*)&va0;
        const v2f* pa1 = (const v2f*)&va1;
        const v2f* pb0 = (const v2f*)&vb0;
        const v2f* pb1 = (const v2f*)&vb1;
        const v2f wa0 = {ea.w0, ea.w0}, wa1 = {ea.w1, ea.w1};
        const v2f wb0 = {eb.w0, eb.w0}, wb1 = {eb.w1, eb.w1};

        accA0 = __builtin_elementwise_fma(wa0, pa0[0], accA0);
        accA1 = __builtin_elementwise_fma(wa0, pa0[1], accA1);
        accA0 = __builtin_elementwise_fma(wa1, pa1[0], accA0);
        accA1 = __builtin_elementwise_fma(wa1, pa1[1], accA1);
        accB0 = __builtin_elementwise_fma(wb0, pb0[0], accB0);
        accB1 = __builtin_elementwise_fma(wb0, pb0[1], accB1);
        accB0 = __builtin_elementwise_fma(wb1, pb1[0], accB0);
        accB1 = __builtin_elementwise_fma(wb1, pb1[1], accB1);
    }

    const float invA = 1.f / (nrmtab[wave]     + 1e-11f);
    const float invB = 1.f / (nrmtab[wave + 4] + 1e-11f);
    const int yA = ybase + wave;
    const int yB = ybase + wave + 4;
    const size_t oA = (((size_t)b * L + x) * L + yA) * L + zq * 4;
    const size_t oB = (((size_t)b * L + x) * L + yB) * L + zq * 4;
    *reinterpret_cast<float4*>(out + oA) =
        make_float4(accA0.x * invA, accA0.y * invA, accA1.x * invA, accA1.y * invA);
    *reinterpret_cast<float4*>(out + oB) =
        make_float4(accB0.x * invB, accB0.y * invB, accB1.x * invB, accB1.y * invB);
}

} // namespace

extern "C" void kernel_launch(void* const* d_in, const int* in_sizes, int n_in,
                              void* d_out, int out_size, void* d_ws, size_t ws_size,
                              hipStream_t stream) {
    const float* image  = (const float*)d_in[0];
    const float* angles = (const float*)d_in[1];
    float* out = (float*)d_out;
    (void)in_sizes; (void)n_in; (void)out_size; (void)d_ws; (void)ws_size;

    dim3 grid(L / 8, L);   // 16 x 128 = 2048 blocks, 8 (x,y) pairs each
    bp_kernel<<<grid, 256, 0, stream>>>(image, angles, out);
}

// Round 3
// 171.372 us; speedup vs baseline: 1.1120x; 1.1120x over previous
//
#include <hip/hip_runtime.h>
#include <hip/hip_fp16.h>

namespace {

constexpr int L           = 128;
constexpr int NANG        = 120;
constexpr int SLICE_BYTES = L * L * 4;           // 65536
constexpr int ROW_BYTES   = L * 4;               // 512
constexpr int NSLOT       = 16;                  // padded row slots per b (max needed 14)
constexpr int STAGE_BYTES = 2 * NSLOT * ROW_BYTES; // 16 KiB per buffer

typedef float v2f __attribute__((ext_vector_type(2)));

// Block: 512 threads = 8 waves, covering an 8(x) x 4(y) tile of output points.
// Wave w owns x = xb + w and the 4 y's; lane: b = lane>>5, zq = lane&31 (float4 over z).
// Per angle: r0-row gather served from LDS-staged rows (double-buffered
// global_load_lds), r1-row gather served directly from global (L1-hot) --
// splits traffic across the LDS and vmem pipes.
__global__ __launch_bounds__(512, 4) void bp_kernel(
    const float* __restrict__ image,   // [2,120,128,128] f32
    const float* __restrict__ angles,  // [120] degrees
    float* __restrict__ out)           // [2,128,128,128] f32
{
    __shared__ alignas(16) char  stage[2 * STAGE_BYTES];   // 32 KiB
    __shared__ alignas(16) uint2 wtab[8 * NANG * 4];       // 30 KiB: [w][a][j] 8B entries
    __shared__ float2 acs[NANG];                            // cos,sin per angle
    __shared__ int    ari[NANG];                            // rlo | nrows<<8
    __shared__ float  nrmtab[32];                           // per-point norm

    const int tid = threadIdx.x;
    const int yb  = blockIdx.x * 4;
    const int xb  = blockIdx.y * 8;
    const float cx = (L - 1) * 0.5f;

    // ---- Phase 0: per-angle rotation params + tile row range ----
    if (tid < NANG) {
        const float phi = -angles[tid] * 0.017453292519943295f;
        float s, c;
        sincosf(phi, &s, &c);
        const float X0 = (float)xb - cx,       X1 = (float)(xb + 7) - cx;
        const float Y0 = (float)yb - cx,       Y1 = (float)(yb + 3) - cx;
        const float a00 = -s * X0 + c * Y0 + cx;
        const float a01 = -s * X0 + c * Y1 + cx;
        const float a10 = -s * X1 + c * Y0 + cx;
        const float a11 = -s * X1 + c * Y1 + cx;
        const float symin = fminf(fminf(a00, a01), fminf(a10, a11));
        const float symax = fmaxf(fmaxf(a00, a01), fmaxf(a10, a11));
        const int rlo = min(max((int)floorf(symin) - 1, 0), L - 1);   // -1: float-eps guard
        const int rhi = min(max((int)floorf(symax) + 2, 0), L - 1);   // +1 row, +1 guard
        acs[tid] = make_float2(c, s);
        ari[tid] = rlo | ((rhi - rlo + 1) << 8);
    }
    if (tid < 32) nrmtab[tid] = 0.f;
    __syncthreads();

    // ---- Phase 1: per-(point, angle) weight entries ----
    for (int e = tid; e < 8 * NANG * 4; e += 512) {
        const int j    = e & 3;
        const int rest = e >> 2;           // w*NANG + a
        const int w    = rest / NANG;
        const int a    = rest - w * NANG;
        const float2 cs = acs[a];
        const int ri    = ari[a];
        const int rlo   = ri & 0xff;
        const int nrows = ri >> 8;
        const float X = (float)(xb + w) - cx;
        const float Y = (float)(yb + j) - cx;
        const float sx =  cs.x * X + cs.y * Y + cx;
        const float sy = -cs.y * X + cs.x * Y + cx;
        const float x0f = floorf(sx), y0f = floorf(sy);
        const float wx = sx - x0f,    wy = sy - y0f;
        const int x0 = (int)x0f, y0 = (int)y0f;
        const float mx0 = (x0 >= 0  && x0 <  L)     ? 1.f : 0.f;
        const float mx1 = (x0 >= -1 && x0 <= L - 2) ? 1.f : 0.f;
        const float my0 = (y0 >= 0  && y0 <  L)     ? 1.f : 0.f;
        const float my1 = (y0 >= -1 && y0 <= L - 2) ? 1.f : 0.f;
        const float A   = (1.f - wx) * mx0 + wx * mx1;
        const float w0f = (1.f - wy) * my0 * A;
        const float w1f = wy * my1 * A;
        const int y0c = min(max(y0, 0), L - 1);
        const int y1c = min(max(y0 + 1, 0), L - 1);
        const int s0  = min(max(y0c - rlo, 0), nrows - 1);   // slot in stage buffer
        __half2 h2 = __floats2half2_rn(w0f, w1f);
        uint2 ent;
        ent.x = *reinterpret_cast<unsigned*>(&h2);
        ent.y = (unsigned)s0 | ((unsigned)y1c << 16);
        wtab[(w * NANG + a) * 4 + j] = ent;
        atomicAdd(&nrmtab[w * 4 + j], w0f + w1f);
    }
    __syncthreads();

    // ---- Phase 2: angle loop ----
    const int wave = tid >> 6;
    const int lane = tid & 63;
    const int b    = lane >> 5;
    const int zq   = lane & 31;
    const char* __restrict__ imgc = (const char*)image;
    const unsigned lane_goff = (unsigned)(b * NANG) * SLICE_BYTES + (unsigned)zq * 16u;
    const unsigned lane_lds  = (unsigned)(b * NSLOT) * ROW_BYTES  + (unsigned)zq * 16u;

    v2f acc[4][2];
#pragma unroll
    for (int j = 0; j < 4; ++j) { acc[j][0] = (v2f){0.f, 0.f}; acc[j][1] = (v2f){0.f, 0.f}; }

    // stage rows of angle a1 into buffer `buf` (2 global_load_lds per wave)
    auto stage_fn = [&](int a1, int buf) {
        const int ri    = ari[a1];
        const int rlo   = ri & 0xff;
        const int nm1   = (ri >> 8) - 1;
#pragma unroll
        for (int it = 0; it < 2; ++it) {
            const int u0 = wave * 2 + it * 16;     // even unit; pair never straddles b
            const int bb = it;                     // u0 >> 4
            const int t  = (u0 & 15) + (lane >> 5);
            const int te = min(t, nm1);            // clamp pads duplicate last row
            const unsigned goff = (unsigned)(bb * NANG + a1) * SLICE_BYTES
                                + (unsigned)(rlo + te) * ROW_BYTES
                                + (unsigned)(lane & 31) * 16u;
            const char* gp = imgc + goff;
            char* lp = &stage[buf * STAGE_BYTES + u0 * ROW_BYTES]; // wave-uniform base; HW adds lane*16
            __builtin_amdgcn_global_load_lds(
                (const __attribute__((address_space(1))) unsigned int*)gp,
                (__attribute__((address_space(3))) unsigned int*)lp, 16, 0, 0);
        }
    };

    stage_fn(0, 0);
    __syncthreads();

    for (int a = 0; a < NANG; ++a) {
        if (a + 1 < NANG) stage_fn(a + 1, (a + 1) & 1);

        const int buf = a & 1;
        const uint4* wp = (const uint4*)&wtab[(wave * NANG + a) * 4];
        const uint4 e01 = wp[0];
        const uint4 e23 = wp[1];
        const unsigned abytes = (unsigned)a * SLICE_BYTES;
        const char* sb = &stage[buf * STAGE_BYTES];

        auto do_point = [&](unsigned elo, unsigned ehi, int j) {
            __half2 h2 = *reinterpret_cast<__half2*>(&elo);
            const float w0 = __half2float(h2.x);
            const float w1 = __half2float(h2.y);
            const unsigned s0 = ehi & 0xffffu;
            const unsigned r1 = ehi >> 16;
            const float4 v0 = *(const float4*)(sb + (lane_lds + s0 * ROW_BYTES));      // LDS route
            const float4 v1 = *(const float4*)(imgc + (lane_goff + abytes + r1 * ROW_BYTES)); // global route
            const v2f w0v = {w0, w0}, w1v = {w1, w1};
            acc[j][0] = __builtin_elementwise_fma(w0v, ((const v2f*)&v0)[0], acc[j][0]);
            acc[j][1] = __builtin_elementwise_fma(w0v, ((const v2f*)&v0)[1], acc[j][1]);
            acc[j][0] = __builtin_elementwise_fma(w1v, ((const v2f*)&v1)[0], acc[j][0]);
            acc[j][1] = __builtin_elementwise_fma(w1v, ((const v2f*)&v1)[1], acc[j][1]);
        };
        do_point(e01.x, e01.y, 0);
        do_point(e01.z, e01.w, 1);
        do_point(e23.x, e23.y, 2);
        do_point(e23.z, e23.w, 3);

        __syncthreads();   // drains stage(a+1) (vmcnt) + guards buffer reuse
    }

    // ---- Epilogue ----
    const int x = xb + wave;
#pragma unroll
    for (int j = 0; j < 4; ++j) {
        const float inv = 1.f / (nrmtab[wave * 4 + j] + 1e-11f);
        const size_t o = (((size_t)(b * L + x)) * L + (size_t)(yb + j)) * L + (size_t)(zq * 4);
        *(float4*)(out + o) = make_float4(acc[j][0].x * inv, acc[j][0].y * inv,
                                          acc[j][1].x * inv, acc[j][1].y * inv);
    }
}

} // namespace

extern "C" void kernel_launch(void* const* d_in, const int* in_sizes, int n_in,
                              void* d_out, int out_size, void* d_ws, size_t ws_size,
                              hipStream_t stream) {
    const float* image  = (const float*)d_in[0];
    const float* angles = (const float*)d_in[1];
    float* out = (float*)d_out;
    (void)in_sizes; (void)n_in; (void)out_size; (void)d_ws; (void)ws_size;

    dim3 grid(L / 4, L / 8);   // 32 x 16 = 512 blocks, 8x4 (x,y) tile each
    bp_kernel<<<grid, 512, 0, stream>>>(image, angles, out);
}

// Round 6
// 146.534 us; speedup vs baseline: 1.3005x; 1.1695x over previous
//
#include <hip/hip_runtime.h>

namespace {

constexpr int L           = 128;
constexpr int NANG        = 120;
constexpr int SLICE_BYTES = L * L * 4;            // 65536
constexpr int ROW_BYTES   = L * 4;                // 512
constexpr int NSLOT       = 16;                   // physical slots per b (12 staged + 4 zero)
constexpr int STAGE_BYTES = NSLOT * 2 * ROW_BYTES; // 16 KiB per buffer (16 slots x 2 b)

typedef __fp16 f16x2 __attribute__((ext_vector_type(2)));
typedef __fp16 f16x4 __attribute__((ext_vector_type(4)));
typedef __fp16 f16x8 __attribute__((ext_vector_type(8)));
typedef float  f32x4 __attribute__((ext_vector_type(4)));

#if __has_builtin(__builtin_amdgcn_mfma_f32_16x16x16f16)
#define USE_K16 1
#else
#define USE_K16 0   // fallback: 16x16x32_f16 (guide-verified present on gfx950)
#endif

// Block: 512 thr = 8 waves. Tile: 8(x) x 4(y) = 32 points, both b, all 128 z.
// Wave w: mt=w&1 (16-point M-tile), b=(w>>1)&1, zg=w>>2 (2 z-halves of 64).
// Per angle: D[point][z] += W[point][slot] * Rows[slot][z]  via MFMA.
__global__ __launch_bounds__(512, 4) void bp_kernel(
    const float* __restrict__ image,   // [2,120,128,128] f32
    const float* __restrict__ angles,  // [120] deg
    float* __restrict__ out)           // [2,128,128,128] f32
{
    __shared__ alignas(16) char  stage[2 * STAGE_BYTES];   // 32 KiB, f32 rows [b][slot][z]
    __shared__ unsigned      wpk[32 * NANG];               // f16 w0 | w1<<16   (15 KiB)
    __shared__ unsigned char spk[32 * NANG];               // s0 | s1<<4        (3.75 KiB)
    __shared__ float2        acs[NANG];
    __shared__ int           ari[NANG];                    // rlo | nrows<<8
    __shared__ alignas(16) float nrmtab[32];

    const int tid = threadIdx.x;
    const int yb  = blockIdx.x * 4;
    const int xb  = blockIdx.y * 8;
    const float cx = (L - 1) * 0.5f;

    // ---- Phase 0: per-angle params + tile row range; zero pad slots; zero norms ----
    if (tid < NANG) {
        const float phi = -angles[tid] * 0.017453292519943295f;
        float s, c;
        sincosf(phi, &s, &c);
        const float X0 = (float)xb - cx,       X1 = (float)(xb + 7) - cx;
        const float Y0 = (float)yb - cx,       Y1 = (float)(yb + 3) - cx;
        const float a00 = -s * X0 + c * Y0 + cx;
        const float a01 = -s * X0 + c * Y1 + cx;
        const float a10 = -s * X1 + c * Y0 + cx;
        const float a11 = -s * X1 + c * Y1 + cx;
        const float symin = fminf(fminf(a00, a01), fminf(a10, a11));
        const float symax = fmaxf(fmaxf(a00, a01), fmaxf(a10, a11));
        const int rlo = min(max((int)floorf(symin) - 1, 0), L - 1);
        const int rhi = min(max((int)floorf(symax) + 2, 0), L - 1);
        acs[tid] = make_float2(c, s);
        ari[tid] = rlo | ((rhi - rlo + 1) << 8);   // nrows <= 12
    }
    if (tid < 32) nrmtab[tid] = 0.f;
    {   // zero slots 12..15 of both b, both buffers (8 KiB) -> one float4 store per thread
        const int region = tid >> 7;               // buf = region>>1, b = region&1
        const int off    = (tid & 127) * 16;
        char* p = &stage[(region >> 1) * STAGE_BYTES + (region & 1) * (NSLOT * ROW_BYTES)
                         + 12 * ROW_BYTES + off];
        *(float4*)p = make_float4(0.f, 0.f, 0.f, 0.f);
    }
    __syncthreads();

    const int wave  = tid >> 6;
    const int lane  = tid & 63;
    const int quad  = lane >> 4;
    const int lhalf = lane & 15;
    const int mt    = wave & 1;
    const int b     = (wave >> 1) & 1;
    const int zg    = wave >> 2;
    const char* __restrict__ imgc = (const char*)image;

    // stage rows of angle a1 into buffer buf. 12 units of 2 rows; XOR-swizzle chunk by slot&4.
    auto stage_fn = [&](int a1, int buf) {
        const int ri  = ari[a1];
        const int rlo = ri & 0xff;
        const int nm1 = (ri >> 8) - 1;
        auto issue = [&](int u) {
            const int bu    = (u >= 6) ? 1 : 0;
            const int spair = 2 * (u - bu * 6);
            const int t     = spair + (lane >> 5);
            const int te    = min(t, nm1);
#if USE_K16
            const unsigned gchunk = (unsigned)(lane & 31) ^ (unsigned)(spair & 4);
#else
            const unsigned gchunk = (unsigned)(lane & 31);
#endif
            const unsigned goff = (unsigned)(bu * NANG + a1) * SLICE_BYTES
                                + (unsigned)(rlo + te) * ROW_BYTES + gchunk * 16u;
            char* lp = &stage[buf * STAGE_BYTES + (bu * NSLOT + spair) * ROW_BYTES];
            __builtin_amdgcn_global_load_lds(
                (const __attribute__((address_space(1))) unsigned int*)(imgc + goff),
                (__attribute__((address_space(3))) unsigned int*)lp, 16, 0, 0);
        };
        issue(wave);
        if (wave < 4) issue(8 + wave);
    };

    stage_fn(0, 0);   // overlaps with phase 1 compute

    // ---- Phase 1: per-(point,angle) f16 weight pair + slot pair ----
    for (int e = tid; e < 32 * NANG; e += 512) {
        const int p = e / NANG;
        const int a = e - p * NANG;
        const float2 cs = acs[a];
        const int ri  = ari[a];
        const int rlo = ri & 0xff;
        const float X = (float)(xb + (p >> 2)) - cx;
        const float Y = (float)(yb + (p & 3)) - cx;
        const float sx =  cs.x * X + cs.y * Y + cx;
        const float sy = -cs.y * X + cs.x * Y + cx;
        const float x0f = floorf(sx), y0f = floorf(sy);
        const float wx = sx - x0f,    wy = sy - y0f;
        const int x0 = (int)x0f, y0 = (int)y0f;
        const float mx0 = (x0 >= 0  && x0 <  L)     ? 1.f : 0.f;
        const float mx1 = (x0 >= -1 && x0 <= L - 2) ? 1.f : 0.f;
        const float my0 = (y0 >= 0  && y0 <  L)     ? 1.f : 0.f;
        const float my1 = (y0 >= -1 && y0 <= L - 2) ? 1.f : 0.f;
        const float A   = (1.f - wx) * mx0 + wx * mx1;
        float w0f = (1.f - wy) * my0 * A;
        float w1f = wy * my1 * A;
        const int y0c = min(max(y0, 0), L - 1);
        const int y1c = min(max(y0 + 1, 0), L - 1);
        const int s0  = min(max(y0c - rlo, 0), 11);
        const int s1  = min(max(y1c - rlo, 0), 11);
        // Slot collision (boundary clamp, e.g. y0 = -1): the sparse-A selector
        // k==s0 shadows k==s1 -> fold the pair so no weight is dropped.
        if (s0 == s1) { w0f += w1f; w1f = 0.f; }
        f16x2 wh = __builtin_amdgcn_cvt_pkrtz(w0f, w1f);
        wpk[e] = *reinterpret_cast<unsigned*>(&wh);
        spk[e] = (unsigned char)(s0 | (s1 << 4));
        atomicAdd(&nrmtab[p], w0f + w1f);
    }
    __syncthreads();   // drains stage(0) + phase-1 tables

    f32x4 acc[4] = {};

    auto body = [&](int a, int bufR) {
        if (a + 1 < NANG) stage_fn(a + 1, bufR ^ 1);

        // A-fragment: A[m=lhalf][k] = (k==s0)?w0 : (k==s1)?w1 : 0
        const int pidx = (mt * 16 + lhalf) * NANG + a;
        const unsigned w01 = wpk[pidx];
        const unsigned sp  = spk[pidx];
        const unsigned s0 = sp & 15u, s1 = sp >> 4;
        const unsigned lo = w01 & 0xffffu, hi = w01 >> 16;
#if USE_K16
        unsigned ea[4];
#pragma unroll
        for (int j = 0; j < 4; ++j) {
            const unsigned k = (unsigned)(quad * 4 + j);
            ea[j] = (k == s0) ? lo : ((k == s1) ? hi : 0u);
        }
        union { unsigned u[2]; f16x4 v; } af;
        af.u[0] = ea[0] | (ea[1] << 16);
        af.u[1] = ea[2] | (ea[3] << 16);
#else
        union { unsigned u[4]; f16x8 v; } af;
#pragma unroll
        for (int t = 0; t < 4; ++t) {
            const unsigned k0 = (unsigned)(quad * 8 + 2 * t);
            const unsigned e0 = (k0 == s0) ? lo : ((k0 == s1) ? hi : 0u);
            const unsigned k1 = k0 + 1;
            const unsigned e1 = (k1 == s0) ? lo : ((k1 == s1) ? hi : 0u);
            af.u[t] = e0 | (e1 << 16);
        }
#endif
        const char* sbase = &stage[bufR * STAGE_BYTES + b * (NSLOT * ROW_BYTES)];

#pragma unroll
        for (int i = 0; i < 4; ++i) {
            const int zp = (zg * 4 + i) * 16 + lhalf;
#if USE_K16
            const int chunk = zp >> 2, w4 = zp & 3;
            const int pz = (((chunk ^ ((quad & 1) << 2)) << 2) | w4) * 4; // de-swizzle
            const char* pp = sbase + quad * (4 * ROW_BYTES) + pz;
            const float r0 = *(const float*)(pp);
            const float r1 = *(const float*)(pp + 512);
            const float r2 = *(const float*)(pp + 1024);
            const float r3 = *(const float*)(pp + 1536);
            const f16x2 h01 = __builtin_amdgcn_cvt_pkrtz(r0, r1);
            const f16x2 h23 = __builtin_amdgcn_cvt_pkrtz(r2, r3);
            const f16x4 bf = {h01.x, h01.y, h23.x, h23.y};
            acc[i] = __builtin_amdgcn_mfma_f32_16x16x16f16(af.v, bf, acc[i], 0, 0, 0);
#else
            const char* pp = sbase + (quad & 1) * (8 * ROW_BYTES) + zp * 4;
            float r[8];
#pragma unroll
            for (int j = 0; j < 8; ++j) r[j] = *(const float*)(pp + j * 512);
            f16x8 bf;
#pragma unroll
            for (int t = 0; t < 4; ++t) {
                const f16x2 h = __builtin_amdgcn_cvt_pkrtz(r[2 * t], r[2 * t + 1]);
                bf[2 * t] = h.x; bf[2 * t + 1] = h.y;
            }
            acc[i] = __builtin_amdgcn_mfma_f32_16x16x32_f16(af.v, bf, acc[i], 0, 0, 0);
#endif
        }
        __syncthreads();   // staged(a+1) complete + all reads of bufR done
    };

    for (int a = 0; a < NANG; a += 2) {
        body(a, 0);
        body(a + 1, 1);
    }

    // ---- Epilogue: D[row=quad*4+r][col=lhalf] -> out, divided by f32 norm ----
    const float4 nrm4 = *(const float4*)&nrmtab[mt * 16 + quad * 4];
    const float inv0 = 1.f / (nrm4.x + 1e-11f);
    const float inv1 = 1.f / (nrm4.y + 1e-11f);
    const float inv2 = 1.f / (nrm4.z + 1e-11f);
    const float inv3 = 1.f / (nrm4.w + 1e-11f);
#pragma unroll
    for (int i = 0; i < 4; ++i) {
        const int z = (zg * 4 + i) * 16 + lhalf;
        const float iv[4] = {inv0, inv1, inv2, inv3};
#pragma unroll
        for (int r = 0; r < 4; ++r) {
            const int p = mt * 16 + quad * 4 + r;
            const int x = xb + (p >> 2);
            const int y = yb + (p & 3);
            out[(((size_t)(b * L + x)) * L + y) * L + z] = acc[i][r] * iv[r];
        }
    }
}

} // namespace

extern "C" void kernel_launch(void* const* d_in, const int* in_sizes, int n_in,
                              void* d_out, int out_size, void* d_ws, size_t ws_size,
                              hipStream_t stream) {
    const float* image  = (const float*)d_in[0];
    const float* angles = (const float*)d_in[1];
    float* out = (float*)d_out;
    (void)in_sizes; (void)n_in; (void)out_size; (void)d_ws; (void)ws_size;

    dim3 grid(L / 4, L / 8);   // 32 x 16 = 512 blocks = exactly 2 per CU
    bp_kernel<<<grid, 512, 0, stream>>>(image, angles, out);
}